// Round 4
// baseline (484.245 us; speedup 1.0000x reference)
//
#include <hip/hip_runtime.h>

typedef _Float16 half_t;
typedef _Float16 v8h __attribute__((ext_vector_type(8)));
typedef __fp16 pk2 __attribute__((ext_vector_type(2)));   // cvt_pkrtz return type
typedef float v4f __attribute__((ext_vector_type(4)));

#define KIN 7056
#define KP2 7168          // K padded to 4*56*32
#define GM 8192
#define GN 512
#define KSEG 1792         // KP2/4
#define NSTEP 56          // KSEG/32
#define SLICE (8192L * 512)

__device__ __forceinline__ void async16(const void* g, void* l) {
  __builtin_amdgcn_global_load_lds((const __attribute__((address_space(1))) void*)g,
                                   (__attribute__((address_space(3))) void*)l, 16, 0, 0);
}

// ---- W1 (7056x512 f32) -> w1t (512x7168 f16, zero-padded), LDS-tiled transpose ----
__global__ __launch_bounds__(256) void conv_w1t(const float* __restrict__ W1, half_t* __restrict__ w1t) {
  __shared__ float t[32][65];
  int tid = threadIdx.x;
  int k0 = blockIdx.x * 32;       // 224 tiles cover 7168
  int n0 = blockIdx.y * 64;       // 8 tiles cover 512
  #pragma unroll
  for (int rr = 0; rr < 8; rr++) {
    int r = rr * 4 + (tid >> 6);
    int c = tid & 63;
    int k = k0 + r;
    t[r][c] = (k < KIN) ? W1[(long)k * GN + n0 + c] : 0.f;
  }
  __syncthreads();
  int n_l = tid >> 2;
  int k_l = (tid & 3) * 8;
  v8h o;
  #pragma unroll
  for (int j = 0; j < 8; j++) o[j] = (_Float16)t[k_l + j][n_l];   // RNE
  *(v8h*)&w1t[(long)(n0 + n_l) * KP2 + k0 + k_l] = o;
}

// ---- small setup: compact W2[:,0:8] and fused U = RZ*RY*RX per (layer,qubit) ----
__global__ __launch_bounds__(256) void small_setup(const float* __restrict__ W2, const float* __restrict__ qp,
                                                   float* __restrict__ w2c, float* __restrict__ umat) {
  int t = threadIdx.x;
  for (int i = t; i < 512; i += 256) {
    #pragma unroll
    for (int j = 0; j < 8; j++) w2c[i * 8 + j] = W2[i * 256 + j];
  }
  if (t < 24) {   // t = layer*8 + qubit
    float a2 = qp[t * 3 + 0] * 0.5f;
    float b2 = qp[t * 3 + 1] * 0.5f;
    float g2 = qp[t * 3 + 2] * 0.5f;
    float ca = cosf(a2), sa = sinf(a2);
    float cb = cosf(b2), sb = sinf(b2);
    float cg = cosf(g2), sg = sinf(g2);
    float m00r = cb * ca, m00i =  sb * sa;
    float m01r = -sb * ca, m01i = -cb * sa;
    float m10r =  sb * ca, m10i = -cb * sa;
    float m11r =  cb * ca, m11i = -sb * sa;
    float* u = umat + t * 8;
    u[0] = m00r * cg + m00i * sg;  u[1] = m00i * cg - m00r * sg;
    u[2] = m01r * cg + m01i * sg;  u[3] = m01i * cg - m01r * sg;
    u[4] = m10r * cg - m10i * sg;  u[5] = m10i * cg + m10r * sg;
    u[6] = m11r * cg - m11i * sg;  u[7] = m11i * cg + m11r * sg;
  }
}

// ---- GEMM1: K-split-4, double-buffered LDS, f16 tiles, A converted in staging ----
// bid: m = bid&63 (fast -> consecutive blocks share the same B panel), g = bid>>6,
//      n = g&3, kc = g>>2. 1024 blocks = 4 blocks/CU (LDS 32 KB each).
// LDS layout (both tiles): (row, chunk c, j) at row*32 + (c ^ ((row>>1)&3))*8 + j
//   -> ds_read_b128 of a fragment hits all 32 banks exactly 8x (minimum) = conflict-free.
__global__ __launch_bounds__(256, 4) void gemm1(const float* __restrict__ A, const half_t* __restrict__ B,
                                                float* __restrict__ P) {
  __shared__ half_t Ash[2][128 * 32];
  __shared__ half_t Bsh[2][128 * 32];
  int tid = threadIdx.x, lane = tid & 63, wave = tid >> 6;
  int bid = blockIdx.x;
  int m0 = (bid & 63) * 128;
  int g = bid >> 6;
  int n0 = (g & 3) * 128;
  int kc = g >> 2;
  int kbeg = kc * KSEG;

  int wm = (wave & 1) * 64;
  int wn = (wave >> 1) * 64;
  int lrow = lane & 15;
  int lkg = lane >> 4;

  // staging decode: slot s = rr*256+tid -> row = s>>2, cstore = s&3, csrc = cstore^((row>>1)&3)
  long abase[2]; int acol[2];
  const half_t* bsrc[2];
  #pragma unroll
  for (int rr = 0; rr < 2; rr++) {
    int s = rr * 256 + tid;
    int row = s >> 2;
    int csrc = (s & 3) ^ ((row >> 1) & 3);
    abase[rr] = (long)(m0 + row) * KIN;
    acol[rr] = csrc * 8;
    bsrc[rr] = B + (long)(n0 + row) * KP2 + kbeg + csrc * 8;
  }

  v4f acc[4][4];
  #pragma unroll
  for (int i = 0; i < 4; i++)
    #pragma unroll
    for (int j = 0; j < 4; j++)
      acc[i][j] = (v4f){0.f, 0.f, 0.f, 0.f};

  v4f ra[2][2];
  // prologue: load A(0), issue B(0) -> buf0, convert+write A(0) -> buf0
  #pragma unroll
  for (int rr = 0; rr < 2; rr++) {
    int col = kbeg + acol[rr];
    col = col > KIN - 8 ? KIN - 8 : col;   // finite junk; B zero-padded kills it
    const float* src = A + abase[rr] + col;
    ra[rr][0] = *(const v4f*)src;
    ra[rr][1] = *(const v4f*)(src + 4);
  }
  #pragma unroll
  for (int rr = 0; rr < 2; rr++) async16(bsrc[rr], &Bsh[0][(rr * 256 + tid) * 8]);
  #pragma unroll
  for (int rr = 0; rr < 2; rr++) {
    union { v8h v; pk2 h[4]; } u;
    u.h[0] = __builtin_amdgcn_cvt_pkrtz(ra[rr][0][0], ra[rr][0][1]);
    u.h[1] = __builtin_amdgcn_cvt_pkrtz(ra[rr][0][2], ra[rr][0][3]);
    u.h[2] = __builtin_amdgcn_cvt_pkrtz(ra[rr][1][0], ra[rr][1][1]);
    u.h[3] = __builtin_amdgcn_cvt_pkrtz(ra[rr][1][2], ra[rr][1][3]);
    *(v8h*)&Ash[0][(rr * 256 + tid) * 8] = u.v;
  }
  asm volatile("s_waitcnt vmcnt(0)" ::: "memory");
  __syncthreads();

  for (int k = 0; k < NSTEP; k++) {
    int p = k & 1;
    int kn = (k + 1 < NSTEP) ? (k + 1) : k;   // last iter: harmless re-load into dead buffer
    int kofs = kbeg + kn * 32;
    // issue A global loads for next step first (so ra-use waits leave B async in flight)
    #pragma unroll
    for (int rr = 0; rr < 2; rr++) {
      int col = kofs + acol[rr];
      col = col > KIN - 8 ? KIN - 8 : col;
      const float* src = A + abase[rr] + col;
      ra[rr][0] = *(const v4f*)src;
      ra[rr][1] = *(const v4f*)(src + 4);
    }
    // issue B async for next step into the other buffer
    #pragma unroll
    for (int rr = 0; rr < 2; rr++) async16(bsrc[rr] + kn * 32, &Bsh[1 - p][(rr * 256 + tid) * 8]);

    // compute current step from buf p
    v8h af[4], bf[4];
    #pragma unroll
    for (int i = 0; i < 4; i++) {
      int row = wm + i * 16 + lrow;
      af[i] = *(const v8h*)&Ash[p][row * 32 + (lkg ^ ((row >> 1) & 3)) * 8];
    }
    #pragma unroll
    for (int j = 0; j < 4; j++) {
      int row = wn + j * 16 + lrow;
      bf[j] = *(const v8h*)&Bsh[p][row * 32 + (lkg ^ ((row >> 1) & 3)) * 8];
    }
    #pragma unroll
    for (int i = 0; i < 4; i++)
      #pragma unroll
      for (int j = 0; j < 4; j++)
        acc[i][j] = __builtin_amdgcn_mfma_f32_16x16x32_f16(af[i], bf[j], acc[i][j], 0, 0, 0);

    // convert + write next A into buf 1-p (global loads had the whole compute phase to land)
    #pragma unroll
    for (int rr = 0; rr < 2; rr++) {
      union { v8h v; pk2 h[4]; } u;
      u.h[0] = __builtin_amdgcn_cvt_pkrtz(ra[rr][0][0], ra[rr][0][1]);
      u.h[1] = __builtin_amdgcn_cvt_pkrtz(ra[rr][0][2], ra[rr][0][3]);
      u.h[2] = __builtin_amdgcn_cvt_pkrtz(ra[rr][1][0], ra[rr][1][1]);
      u.h[3] = __builtin_amdgcn_cvt_pkrtz(ra[rr][1][2], ra[rr][1][3]);
      *(v8h*)&Ash[1 - p][(rr * 256 + tid) * 8] = u.v;
    }
    __syncthreads();
  }

  float* Pk = P + kc * SLICE;
  int crow = lkg * 4;   // C/D: col=lane&15, row=(lane>>4)*4+v
  #pragma unroll
  for (int j = 0; j < 4; j++) {
    int col = n0 + wn + j * 16 + lrow;
    #pragma unroll
    for (int i = 0; i < 4; i++) {
      int rbase = m0 + wm + i * 16 + crow;
      #pragma unroll
      for (int v = 0; v < 4; v++)
        Pk[(long)(rbase + v) * GN + col] = acc[i][j][v];
    }
  }
}

// ---- quantum sim + angles prologue + post-MLP: one wave per sample ----
__device__ __forceinline__ void cnot_lane(float ar[4], float ai[4], int lane, int cm, int tm) {
  bool c = (lane & cm) != 0;
  #pragma unroll
  for (int r = 0; r < 4; r++) {
    float pr = __shfl_xor(ar[r], tm);
    float pi = __shfl_xor(ai[r], tm);
    ar[r] = c ? pr : ar[r];
    ai[r] = c ? pi : ai[r];
  }
}

__device__ __forceinline__ void rot_lane(float ar[4], float ai[4], int lane, int mk, const float u[8]) {
  bool hi = (lane & mk) != 0;
  float csr = hi ? u[6] : u[0], csi = hi ? u[7] : u[1];
  float cpr = hi ? u[4] : u[2], cpi = hi ? u[5] : u[3];
  #pragma unroll
  for (int r = 0; r < 4; r++) {
    float pr = __shfl_xor(ar[r], mk);
    float pi = __shfl_xor(ai[r], mk);
    float nr = csr * ar[r] - csi * ai[r] + cpr * pr - cpi * pi;
    float ni = csr * ai[r] + csi * ar[r] + cpr * pi + cpi * pr;
    ar[r] = nr; ai[r] = ni;
  }
}

__device__ __forceinline__ void apply2(const float u[8], float& x0r, float& x0i, float& x1r, float& x1i) {
  float n0r = u[0] * x0r - u[1] * x0i + u[2] * x1r - u[3] * x1i;
  float n0i = u[0] * x0i + u[1] * x0r + u[2] * x1i + u[3] * x1r;
  float n1r = u[4] * x0r - u[5] * x0i + u[6] * x1r - u[7] * x1i;
  float n1i = u[4] * x0i + u[5] * x0r + u[6] * x1i + u[7] * x1r;
  x0r = n0r; x0i = n0i; x1r = n1r; x1i = n1i;
}

__global__ __launch_bounds__(256) void quantum_post(
    const float* __restrict__ P, const float* __restrict__ b1, const float* __restrict__ w2c,
    const float* __restrict__ b2, const float* __restrict__ umat,
    const float* __restrict__ W1p, const float* __restrict__ b1p,
    const float* __restrict__ W2p, const float* __restrict__ b2p,
    const float* __restrict__ W3p, const float* __restrict__ b3p,
    float* __restrict__ out) {
  __shared__ float h2s[4][128];
  int tid = threadIdx.x;
  int wave = tid >> 6, lane = tid & 63;
  int s = blockIdx.x * 4 + wave;

  // ---- angles prologue, fully coalesced: lane owns h-indices i = lane + 64m
  long pbase = (long)s * GN + lane;
  float a[8] = {0, 0, 0, 0, 0, 0, 0, 0};
  #pragma unroll
  for (int m = 0; m < 8; m++) {
    int i = lane + 64 * m;
    float hv = b1[i];
    #pragma unroll
    for (int c = 0; c < 4; c++) hv += P[c * SLICE + pbase + 64 * m];
    hv = fmaxf(hv, 0.f);
    v4f wlo = *(const v4f*)&w2c[i * 8];
    v4f whi = *(const v4f*)&w2c[i * 8 + 4];
    #pragma unroll
    for (int j = 0; j < 4; j++) { a[j] += hv * wlo[j]; a[j + 4] += hv * whi[j]; }
  }
  #pragma unroll
  for (int m = 1; m < 64; m <<= 1)
    #pragma unroll
    for (int j = 0; j < 8; j++) a[j] += __shfl_xor(a[j], m);
  float f[8];
  #pragma unroll
  for (int j = 0; j < 8; j++) {
    float z = a[j] + b2[j];
    float ex = __expf(2.f * z);
    f[j] = 1.f - 2.f / (ex + 1.f);   // tanh(z)
  }

  // ---- initial product state: RY(f*pi) H |0>
  float v0[8], v1[8];
  #pragma unroll
  for (int q = 0; q < 8; q++) {
    float ang = f[q] * 1.57079632679f;
    float sn, cs;
    __sincosf(ang, &sn, &cs);
    v0[q] = (cs - sn) * 0.70710678118f;
    v1[q] = (cs + sn) * 0.70710678118f;
  }
  float ar[4], ai[4];
  #pragma unroll
  for (int r = 0; r < 4; r++) {
    int i = lane * 4 + r;   // qubit w bit = bit (7-w) of i
    float prod = 1.f;
    #pragma unroll
    for (int q = 0; q < 8; q++) prod *= ((i >> (7 - q)) & 1) ? v1[q] : v0[q];
    ar[r] = prod; ai[r] = 0.f;
  }

  #pragma unroll
  for (int L = 0; L < 3; L++) {
    cnot_lane(ar, ai, lane, 32, 16);
    cnot_lane(ar, ai, lane, 8, 4);
    cnot_lane(ar, ai, lane, 2, 1);
    { float t = ar[2]; ar[2] = ar[3]; ar[3] = t; t = ai[2]; ai[2] = ai[3]; ai[3] = t; }
    cnot_lane(ar, ai, lane, 16, 8);
    cnot_lane(ar, ai, lane, 4, 2);
    {
      bool c = (lane & 1) != 0;
      #pragma unroll
      for (int r = 0; r < 2; r++) {
        float t0 = ar[r], t1 = ar[r + 2];
        ar[r] = c ? t1 : t0; ar[r + 2] = c ? t0 : t1;
        t0 = ai[r]; t1 = ai[r + 2];
        ai[r] = c ? t1 : t0; ai[r + 2] = c ? t0 : t1;
      }
    }
    #pragma unroll
    for (int q = 0; q < 6; q++) {
      float u[8];
      #pragma unroll
      for (int c = 0; c < 8; c++) u[c] = umat[(L * 8 + q) * 8 + c];
      rot_lane(ar, ai, lane, 32 >> q, u);
    }
    {
      float u[8];
      #pragma unroll
      for (int c = 0; c < 8; c++) u[c] = umat[(L * 8 + 6) * 8 + c];
      apply2(u, ar[0], ai[0], ar[2], ai[2]);
      apply2(u, ar[1], ai[1], ar[3], ai[3]);
      #pragma unroll
      for (int c = 0; c < 8; c++) u[c] = umat[(L * 8 + 7) * 8 + c];
      apply2(u, ar[0], ai[0], ar[1], ai[1]);
      apply2(u, ar[2], ai[2], ar[3], ai[3]);
    }
  }

  float p0 = ar[0] * ar[0] + ai[0] * ai[0];
  float p1 = ar[1] * ar[1] + ai[1] * ai[1];
  float p2 = ar[2] * ar[2] + ai[2] * ai[2];
  float p3 = ar[3] * ar[3] + ai[3] * ai[3];
  float psum = p0 + p1 + p2 + p3;
  float e[8];
  #pragma unroll
  for (int q = 0; q < 6; q++) e[q] = (lane & (32 >> q)) ? -psum : psum;
  e[6] = p0 + p1 - p2 - p3;
  e[7] = p0 - p1 + p2 - p3;
  #pragma unroll
  for (int m = 1; m < 64; m <<= 1)
    #pragma unroll
    for (int q = 0; q < 8; q++) e[q] += __shfl_xor(e[q], m);

  float h2a = b1p[lane], h2b = b1p[lane + 64];
  #pragma unroll
  for (int k = 0; k < 8; k++) {
    h2a += e[k] * W1p[k * 128 + lane];
    h2b += e[k] * W1p[k * 128 + lane + 64];
  }
  h2s[wave][lane] = fmaxf(h2a, 0.f);
  h2s[wave][lane + 64] = fmaxf(h2b, 0.f);
  __syncthreads();
  float h3 = b2p[lane];
  #pragma unroll 8
  for (int k = 0; k < 128; k++) h3 += h2s[wave][k] * W2p[k * 64 + lane];
  h3 = fmaxf(h3, 0.f);
  float o[6];
  #pragma unroll
  for (int j = 0; j < 6; j++) o[j] = h3 * W3p[lane * 6 + j];
  #pragma unroll
  for (int m = 1; m < 64; m <<= 1)
    #pragma unroll
    for (int j = 0; j < 6; j++) o[j] += __shfl_xor(o[j], m);
  if (lane == 0) {
    #pragma unroll
    for (int j = 0; j < 6; j++) out[(long)s * 6 + j] = o[j] + b3p[j];
  }
}

extern "C" void kernel_launch(void* const* d_in, const int* in_sizes, int n_in,
                              void* d_out, int out_size, void* d_ws, size_t ws_size,
                              hipStream_t stream) {
  const float* x   = (const float*)d_in[0];
  const float* W1  = (const float*)d_in[1];
  const float* b1  = (const float*)d_in[2];
  const float* W2  = (const float*)d_in[3];
  const float* b2  = (const float*)d_in[4];
  const float* qp  = (const float*)d_in[5];
  const float* W1p = (const float*)d_in[6];
  const float* b1p = (const float*)d_in[7];
  const float* W2p = (const float*)d_in[8];
  const float* b2p = (const float*)d_in[9];
  const float* W3p = (const float*)d_in[10];
  const float* b3p = (const float*)d_in[11];
  float* out = (float*)d_out;

  char* ws = (char*)d_ws;
  half_t* w1t  = (half_t*)(ws);                    // 512*7168*2 = 7,340,032
  float*  w2c  = (float*)(ws + 7340032);           // 16,384
  float*  umat = (float*)(ws + 7356416);           // 768
  float*  P    = (float*)(ws + 7357440);           // 4*8192*512*4 = 67,108,864

  conv_w1t<<<dim3(224, 8), 256, 0, stream>>>(W1, w1t);
  small_setup<<<1, 256, 0, stream>>>(W2, qp, w2c, umat);
  gemm1<<<1024, 256, 0, stream>>>(x, w1t, P);
  quantum_post<<<2048, 256, 0, stream>>>(P, b1, w2c, b2, umat,
                                         W1p, b1p, W2p, b2p, W3p, b3p, out);
}